// Round 3
// baseline (1185.716 us; speedup 1.0000x reference)
//
#include <hip/hip_runtime.h>
#include <stdint.h>

#define P_MOD       2013265921u   // 15*2^27 + 1
#define TWO32_MOD_P 268435454u    // 2^32 mod P

__device__ __forceinline__ uint32_t submod(uint32_t a, uint32_t b) {
    return (a >= b) ? (a - b) : (a - b + P_MOD);
}

// Least nonnegative residue mod P of the INT32 (two's-complement) interpretation
// of z. Emulates numpy int32 wraparound followed by numpy-style `% P`
// (divisor-sign remainder). z < 2^32 < 3P, so two conditional subtracts give
// z mod P; the sign-bit correction subtracts 2^32 mod P.
__device__ __forceinline__ uint32_t wrapmod(uint32_t z) {
    uint32_t r = (z >= P_MOD) ? z - P_MOD : z;
    r = (r >= P_MOD) ? r - P_MOD : r;
    if (z & 0x80000000u) r = submod(r, TWO32_MOD_P);
    return r;
}

// emulate numpy int32: (a * b) wrapped to 32 bits, then % P
__device__ __forceinline__ uint32_t mulmod_wrap(uint32_t a, uint32_t b) {
    return wrapmod(a * b);        // unsigned mul wraps mod 2^32 = lo32
}

// ---------------------------------------------------------------------------
// Pass A: stages m=2 .. 2^13. Each block: 8192 contiguous outputs, gathered
// bit-reversed from input, optional coset pre-scale, 13 radix-2 stages in LDS.
// ---------------------------------------------------------------------------
__global__ __launch_bounds__(256) void ntt_passA(
    const uint32_t* __restrict__ in,
    const uint32_t* __restrict__ tw,
    const uint32_t* __restrict__ itw,
    const uint32_t* __restrict__ cp,
    const int* __restrict__ f_intt,
    const int* __restrict__ f_coset,
    uint32_t* __restrict__ out,
    int logn)
{
    __shared__ uint32_t sh[8192];
    const int tid   = threadIdx.x;
    const int batch = blockIdx.y;
    const long long base = (long long)batch << logn;
    const int blk0  = blockIdx.x * 8192;
    const int revsh = 32 - logn;

    const int is_intt  = f_intt[0];
    const int is_coset = f_coset[0];
    const uint32_t* __restrict__ twsel = is_intt ? itw : tw;
    const bool do_coset = (!is_intt) && (is_coset != 0);

    // gather (bit-reversed) + optional coset pre-scale (int32-wrap semantics)
    for (int it = 0; it < 32; ++it) {
        int t = tid + it * 256;
        uint32_t i = (uint32_t)(blk0 + t);
        uint32_t ridx = __brev(i) >> revsh;
        uint32_t x = in[base + ridx];
        if (do_coset) x = mulmod_wrap(x, cp[ridx]);
        sh[t] = x;
    }
    __syncthreads();

    // 13 radix-2 stages in LDS, int32-wrap butterflies
    for (int pa = 1; pa <= 13; ++pa) {
        const int hs   = 1 << (pa - 1);
        const int twsh = logn - pa;
        for (int it = 0; it < 16; ++it) {
            int bf  = tid + it * 256;              // 0..4095
            int j   = bf & (hs - 1);
            int blk = bf >> (pa - 1);
            int iu  = (blk << pa) | j;
            int iv  = iu + hs;
            uint32_t u = sh[iu];
            uint32_t v = sh[iv];
            uint32_t w = twsel[(uint32_t)j << twsh];
            uint32_t t2 = mulmod_wrap(v, w);       // W(lo32(v*w))
            sh[iu] = wrapmod(u + t2);              // W(u+t2), u+t2 < 2P < 2^32
            sh[iv] = wrapmod(u - t2);              // W of two's-complement diff
        }
        __syncthreads();
    }

    for (int it = 0; it < 32; ++it) {
        int t = tid + it * 256;
        out[base + blk0 + t] = sh[t];
    }
}

// ---------------------------------------------------------------------------
// Pass B: stages m=2^14 .. 2^22, in place. Tile: 512 strided (stride 2^13)
// x 16 contiguous lows; LDS pitch 17 kills bank conflicts.
// ---------------------------------------------------------------------------
__global__ __launch_bounds__(256) void ntt_passB(
    const uint32_t* __restrict__ tw,
    const uint32_t* __restrict__ itw,
    const uint32_t* __restrict__ icp,
    const int* __restrict__ f_intt,
    const int* __restrict__ f_coset,
    uint32_t* __restrict__ data,
    uint32_t ninv, int logn)
{
    __shared__ uint32_t sh[512 * 17];
    const int tid   = threadIdx.x;
    const int batch = blockIdx.y;
    const long long base = (long long)batch << logn;
    const int lowbase = blockIdx.x * 16;

    const int is_intt  = f_intt[0];
    const int is_coset = f_coset[0];
    const uint32_t* __restrict__ twsel = is_intt ? itw : tw;

    for (int it = 0; it < 32; ++it) {
        int e  = tid + it * 256;
        int lo = e & 15;
        int s  = e >> 4;
        sh[s * 17 + lo] = data[base + ((long long)s << 13) + lowbase + lo];
    }
    __syncthreads();

    for (int p = 0; p <= 8; ++p) {
        const int hs   = 1 << p;
        const int twsh = 8 - p;
        for (int it = 0; it < 16; ++it) {
            int bf   = tid + it * 256;     // 256 s-pairs x 16 lows
            int lo   = bf & 15;
            int sb   = bf >> 4;            // 0..255
            int sj   = sb & (hs - 1);
            int sblk = sb >> p;
            int su   = (sblk << (p + 1)) | sj;
            int sv   = su + hs;
            uint32_t u = sh[su * 17 + lo];
            uint32_t v = sh[sv * 17 + lo];
            uint32_t jg = (uint32_t)(lowbase + lo) + ((uint32_t)sj << 13);
            uint32_t w  = twsel[jg << twsh];
            uint32_t t2 = mulmod_wrap(v, w);
            sh[su * 17 + lo] = wrapmod(u + t2);
            sh[sv * 17 + lo] = wrapmod(u - t2);
        }
        __syncthreads();
    }

    // store (+ INTT post-scales, dead in this bench but int32-wrap-correct)
    for (int it = 0; it < 32; ++it) {
        int e  = tid + it * 256;
        int lo = e & 15;
        int s  = e >> 4;
        uint32_t val = sh[s * 17 + lo];
        long long gi = ((long long)s << 13) + lowbase + lo;
        if (is_intt) {
            val = mulmod_wrap(val, ninv);              // * N^{-1}  (wrap semantics)
            if (is_coset) val = mulmod_wrap(val, icp[gi]);  // * g^{-i}
        }
        data[base + gi] = val;
    }
}

extern "C" void kernel_launch(void* const* d_in, const int* in_sizes, int n_in,
                              void* d_out, int out_size, void* d_ws, size_t ws_size,
                              hipStream_t stream) {
    const uint32_t* in  = (const uint32_t*)d_in[0];
    const uint32_t* tw  = (const uint32_t*)d_in[1];
    const uint32_t* itw = (const uint32_t*)d_in[2];
    const uint32_t* cp  = (const uint32_t*)d_in[3];
    const uint32_t* icp = (const uint32_t*)d_in[4];
    // d_in[5] = bitrev (unused; computed via __brev on device)
    const int* f_intt  = (const int*)d_in[6];
    const int* f_coset = (const int*)d_in[7];

    const int N = in_sizes[5];            // bitrev has N entries
    const int B = in_sizes[0] / N;
    int logn = 0; while ((1 << logn) < N) ++logn;

    // N^{-1} mod P (host-side, exact)
    const unsigned long long P = 2013265921ull;
    unsigned long long b = (unsigned long long)N % P, e = P - 2, acc = 1;
    while (e) { if (e & 1) acc = acc * b % P; b = b * b % P; e >>= 1; }
    const uint32_t ninv = (uint32_t)acc;

    uint32_t* out = (uint32_t*)d_out;

    dim3 blk(256);
    dim3 gA(N / 8192, B);
    ntt_passA<<<gA, blk, 0, stream>>>(in, tw, itw, cp, f_intt, f_coset, out, logn);
    dim3 gB(N / 8192, B);
    ntt_passB<<<gB, blk, 0, stream>>>(tw, itw, icp, f_intt, f_coset, out, ninv, logn);
}